// Round 10
// baseline (7693.947 us; speedup 1.0000x reference)
//
#include <hip/hip_runtime.h>
#include <stdint.h>

#define Bq 64
#define Tq 512
#define Hq 512
#define G3 1536

typedef unsigned short u16;
typedef uint32_t u32;
typedef unsigned long long u64;
typedef __attribute__((ext_vector_type(8))) short bf16x8;
typedef __attribute__((ext_vector_type(4))) float f32x4;

__device__ __forceinline__ float bf2f(u16 v){ unsigned u = ((unsigned)v)<<16; float f; __builtin_memcpy(&f,&u,4); return f; }
__device__ __forceinline__ u16 f2bf(float f){ unsigned u; __builtin_memcpy(&u,&f,4); u += 0x7fffu + ((u>>16)&1u); return (u16)(u>>16); }

// dtype detector: flag=1 if inputs are bf16, 0 if fp32.
__global__ void detect_k(const u16* __restrict__ xs, int* __restrict__ flag){
  __shared__ int cnt;
  if (threadIdx.x==0) cnt = 0;
  __syncthreads();
  int good = 0;
  for (int i = threadIdx.x; i < 4096; i += 256) {
    u16 v = xs[2*i];
    int e = (v>>7)&0xFF;
    if (e==0 || (e>=100 && e<=140)) good++;
  }
  atomicAdd(&cnt, good);
  __syncthreads();
  if (threadIdx.x==0) flag[0] = (cnt > 3600) ? 1 : 0;
}

// ---------------------------------------------------------------------------
// gx GEMM: gx[dir][t][b][n] = A[b*T+t][:] . W[dir][n][:] + bias[dir][n]
// AMODE 0: A dtype per flag (fp32 -> split hi/lo bf16). AMODE 1: A bf16 (hs0).
// OUTF32: gx stored fp32 (1) or bf16 (0).
// ---------------------------------------------------------------------------
template<int K, int AMODE, int OUTF32>
__global__ __launch_bounds__(256,1) void gemm_gx(const void* __restrict__ Araw,
        const void* __restrict__ Wraw, const void* __restrict__ braw,
        void* __restrict__ outraw, const int* __restrict__ dflag)
{
  __shared__ __align__(16) u16 Ah[64*72];
  __shared__ __align__(16) u16 Al[64*72];
  __shared__ __align__(16) u16 Wh[64*72];
  __shared__ __align__(16) u16 Wl[64*72];
  const int bf16in = dflag[0];
  const bool useAlo = (AMODE==0) && !bf16in;
  const bool useWlo = !bf16in;
  const int dir = blockIdx.z;
  const int tid = threadIdx.x;
  const int m0 = blockIdx.x*64, n0 = blockIdx.y*64;
  const int wave = tid>>6, lane = tid&63;
  const int wm = (wave>>1)*32, wn = (wave&1)*32;
  f32x4 acc[2][2] = {};

  for (int kb=0; kb<K/64; kb++) {
    if (AMODE==0 && !bf16in) {
      const float* Af = (const float*)Araw;
      #pragma unroll
      for (int it=0; it<4; it++) {
        int c = it*256 + tid;
        int r = c>>4, cc = (c&15)*4;
        float4 v = *(const float4*)&Af[(size_t)(m0+r)*K + kb*64 + cc];
        u16 h0=f2bf(v.x), h1=f2bf(v.y), h2=f2bf(v.z), h3=f2bf(v.w);
        *(ushort4*)&Ah[r*72+cc] = make_ushort4(h0,h1,h2,h3);
        *(ushort4*)&Al[r*72+cc] = make_ushort4(
            f2bf(v.x-bf2f(h0)), f2bf(v.y-bf2f(h1)),
            f2bf(v.z-bf2f(h2)), f2bf(v.w-bf2f(h3)));
      }
    } else {
      const u16* Ab = (const u16*)Araw;
      #pragma unroll
      for (int it=0; it<2; it++) {
        int c = it*256 + tid;
        int r = c>>3, cc = (c&7)*8;
        *(bf16x8*)&Ah[r*72+cc] = *(const bf16x8*)&Ab[(size_t)(m0+r)*K + kb*64 + cc];
      }
    }
    if (!bf16in) {
      const float* Wf = (const float*)Wraw + (size_t)dir*G3*K;
      #pragma unroll
      for (int it=0; it<4; it++) {
        int c = it*256 + tid;
        int r = c>>4, cc = (c&15)*4;
        float4 v = *(const float4*)&Wf[(size_t)(n0+r)*K + kb*64 + cc];
        u16 h0=f2bf(v.x), h1=f2bf(v.y), h2=f2bf(v.z), h3=f2bf(v.w);
        *(ushort4*)&Wh[r*72+cc] = make_ushort4(h0,h1,h2,h3);
        *(ushort4*)&Wl[r*72+cc] = make_ushort4(
            f2bf(v.x-bf2f(h0)), f2bf(v.y-bf2f(h1)),
            f2bf(v.z-bf2f(h2)), f2bf(v.w-bf2f(h3)));
      }
    } else {
      const u16* Wb = (const u16*)Wraw + (size_t)dir*G3*K;
      #pragma unroll
      for (int it=0; it<2; it++) {
        int c = it*256 + tid;
        int r = c>>3, cc = (c&7)*8;
        *(bf16x8*)&Wh[r*72+cc] = *(const bf16x8*)&Wb[(size_t)(n0+r)*K + kb*64 + cc];
      }
    }
    __syncthreads();
    #pragma unroll
    for (int ks=0; ks<2; ks++) {
      int ko = ks*32 + (lane>>4)*8;
      bf16x8 a0 = *(const bf16x8*)&Ah[(wm    + (lane&15))*72 + ko];
      bf16x8 a1 = *(const bf16x8*)&Ah[(wm+16 + (lane&15))*72 + ko];
      bf16x8 b0 = *(const bf16x8*)&Wh[(wn    + (lane&15))*72 + ko];
      bf16x8 b1 = *(const bf16x8*)&Wh[(wn+16 + (lane&15))*72 + ko];
      acc[0][0] = __builtin_amdgcn_mfma_f32_16x16x32_bf16(a0,b0,acc[0][0],0,0,0);
      acc[0][1] = __builtin_amdgcn_mfma_f32_16x16x32_bf16(a0,b1,acc[0][1],0,0,0);
      acc[1][0] = __builtin_amdgcn_mfma_f32_16x16x32_bf16(a1,b0,acc[1][0],0,0,0);
      acc[1][1] = __builtin_amdgcn_mfma_f32_16x16x32_bf16(a1,b1,acc[1][1],0,0,0);
      if (useAlo) {
        bf16x8 c0 = *(const bf16x8*)&Al[(wm    + (lane&15))*72 + ko];
        bf16x8 c1 = *(const bf16x8*)&Al[(wm+16 + (lane&15))*72 + ko];
        acc[0][0] = __builtin_amdgcn_mfma_f32_16x16x32_bf16(c0,b0,acc[0][0],0,0,0);
        acc[0][1] = __builtin_amdgcn_mfma_f32_16x16x32_bf16(c0,b1,acc[0][1],0,0,0);
        acc[1][0] = __builtin_amdgcn_mfma_f32_16x16x32_bf16(c1,b0,acc[1][0],0,0,0);
        acc[1][1] = __builtin_amdgcn_mfma_f32_16x16x32_bf16(c1,b1,acc[1][1],0,0,0);
      }
      if (useWlo) {
        bf16x8 d0 = *(const bf16x8*)&Wl[(wn    + (lane&15))*72 + ko];
        bf16x8 d1 = *(const bf16x8*)&Wl[(wn+16 + (lane&15))*72 + ko];
        acc[0][0] = __builtin_amdgcn_mfma_f32_16x16x32_bf16(a0,d0,acc[0][0],0,0,0);
        acc[0][1] = __builtin_amdgcn_mfma_f32_16x16x32_bf16(a0,d1,acc[0][1],0,0,0);
        acc[1][0] = __builtin_amdgcn_mfma_f32_16x16x32_bf16(a1,d0,acc[1][0],0,0,0);
        acc[1][1] = __builtin_amdgcn_mfma_f32_16x16x32_bf16(a1,d1,acc[1][1],0,0,0);
      }
    }
    __syncthreads();
  }
  #pragma unroll
  for (int i=0;i<2;i++) {
    #pragma unroll
    for (int j=0;j<2;j++) {
      int nn = n0 + wn + j*16 + (lane&15);
      float bv = bf16in ? bf2f(((const u16*)braw)[dir*G3 + nn])
                        : ((const float*)braw)[dir*G3 + nn];
      #pragma unroll
      for (int r=0;r<4;r++) {
        int mm = m0 + wm + i*16 + (lane>>4)*4 + r;
        int b = mm >> 9, t = mm & 511;
        size_t oi = ((size_t)(dir*Tq + t)*Bq + b)*G3 + nn;
        float v = acc[i][j][r] + bv;
        if (OUTF32) ((float*)outraw)[oi] = v;
        else        ((u16*)outraw)[oi]   = f2bf(v);
      }
    }
  }
}

// ---------------------------------------------------------------------------
// Persistent GRU scan. 128 wgs: dir(2) x batch-group(4) x slice(16).
// SINGLE 64-thread wave per block, ZERO LDS. ALL-RMW coherence-point
// protocol (rounds 6-9 PASS, byte-identical): publish exchanges / signal
// adds / poll RMWs / gather RMWs all execute at the MALL; producer ordering
// = per-wave vmcnt drain before signal.
// Round-10 restructure (numerics bit-identical):
//  - W_hh ENTIRELY IN REGISTERS: 96 bf16x8/lane (=384 VGPR), loaded once.
//    __launch_bounds__(64,1) -> 1 wave/SIMD -> up to 512 VGPRs, no spill
//    expected (~490 peak). No wlds, no helper wave, no barriers at all.
//  - gather/MFMA chunk-interleaved (4 chunks of 4 kk, two named 8-u64
//    buffers, fully static indexing) to bound live gather regs at 32.
//    kk stays ascending per accumulator chain -> gh bit-identical.
// ---------------------------------------------------------------------------
template<int LAYER, int GXF32>
__global__ __launch_bounds__(64,1) void gru_scan(const void* __restrict__ whh,
        const void* __restrict__ bhh, const void* __restrict__ gx,
        u16* __restrict__ hs0, void* __restrict__ dout,
        u32* __restrict__ hexw, int* __restrict__ flags,
        const int* __restrict__ dflag)
{
  const int bf16in = dflag[0];
  const int lane = threadIdx.x;           // 0..63
  const int bx  = blockIdx.x;
  const int dir = bx>>6, group=(bx>>4)&3, slice=bx&15;
  const int jbase = slice*32, bg0 = group*16;
  int* fl = flags + (dir*4+group)*16;

  const int j0 = lane&15;
  const int bq = (lane>>4)*4;             // batch base 0,4,8,12
  const int khalf = (lane>>4)*8;          // K sub-offset within 32-wide kk

  // ---- W_hh fragments in registers: wreg[c][g][kk] = row gate*512+jbase+
  //      c*16+j0, cols kk*32+khalf..+8. Same values as prior wlds layout.
  bf16x8 wreg[2][3][16];
  if (!bf16in) {
    const float* wf0 = (const float*)whh + (size_t)dir*G3*Hq;
    #pragma unroll
    for (int c=0;c<2;c++)
    #pragma unroll
    for (int g=0;g<3;g++) {
      const float* wr = wf0 + (size_t)(g*512 + jbase + c*16 + j0)*Hq;
      #pragma unroll
      for (int kk=0;kk<16;kk++) {
        float4 v0 = *(const float4*)&wr[kk*32 + khalf];
        float4 v1 = *(const float4*)&wr[kk*32 + khalf + 4];
        bf16x8 w;
        w[0]=(short)f2bf(v0.x); w[1]=(short)f2bf(v0.y);
        w[2]=(short)f2bf(v0.z); w[3]=(short)f2bf(v0.w);
        w[4]=(short)f2bf(v1.x); w[5]=(short)f2bf(v1.y);
        w[6]=(short)f2bf(v1.z); w[7]=(short)f2bf(v1.w);
        wreg[c][g][kk] = w;
      }
    }
  } else {
    const u16* wb0 = (const u16*)whh + (size_t)dir*G3*Hq;
    #pragma unroll
    for (int c=0;c<2;c++)
    #pragma unroll
    for (int g=0;g<3;g++) {
      const u16* wr = wb0 + (size_t)(g*512 + jbase + c*16 + j0)*Hq;
      #pragma unroll
      for (int kk=0;kk<16;kk++)
        wreg[c][g][kk] = *(const bf16x8*)&wr[kk*32 + khalf];
    }
  }

  // loop-invariant bias regs (both col-halves)
  float bR[2], bZ[2], bN[2];
  #pragma unroll
  for (int c=0;c<2;c++) {
    int off = dir*G3 + jbase + c*16 + j0;
    if (bf16in) { const u16* bb=(const u16*)bhh;
      bR[c]=bf2f(bb[off]); bZ[c]=bf2f(bb[off+512]); bN[c]=bf2f(bb[off+1024]); }
    else { const float* bb=(const float*)bhh;
      bR[c]=bb[off]; bZ[c]=bb[off+512]; bN[c]=bb[off+1024]; }
  }

  float h[2][4] = {};
  float gxr[2][4], gxz[2][4], gxn[2][4];
  auto ldgx = [&](int t_in_){
    #pragma unroll
    for (int c=0;c<2;c++)
    #pragma unroll
    for (int i=0;i<4;i++){
      size_t gb = ((size_t)(dir*Tq + t_in_)*Bq + (bg0 + bq + i))*G3 + jbase + c*16 + j0;
      if (GXF32) { const float* gp=(const float*)gx + gb;
        gxr[c][i]=gp[0]; gxz[c][i]=gp[512]; gxn[c][i]=gp[1024]; }
      else { const u16* gp=(const u16*)gx + gb;
        gxr[c][i]=bf2f(gp[0]); gxz[c][i]=bf2f(gp[512]); gxn[c][i]=bf2f(gp[1024]); }
    }
  };
  ldgx(dir ? (Tq-1) : 0);

  for (int s=0; s<Tq; s++) {
    const int t_in = dir ? (Tq-1-s) : s;
    // poll (lanes 0-15, RMW at MALL); reconvergence = intra-wave barrier.
    if (lane < 16) {
      while (__hip_atomic_fetch_add(&fl[lane], 0, __ATOMIC_RELAXED, __HIP_MEMORY_SCOPE_AGENT) < s) {
        __builtin_amdgcn_s_sleep(1);
      }
    }
    asm volatile("" ::: "memory");   // compiler-only: no hoisting of gathers
    const u32 rb = (u32)(((s&1)*2 + dir)*Bq + bg0)*256u;
    const u32 gbase = rb + (u32)(lane&15)*256u + (u32)((lane>>4)*4);

    // chunked gather (8 u64) / MFMA (4 kk) interleave, all-static indexing
    u64 aA[8], aB[8];
    #pragma unroll
    for (int k2=0;k2<4;k2++) {
      u32 b_ = gbase + (u32)((0+k2)*16);
      aA[2*k2]   = __hip_atomic_fetch_add((u64*)&hexw[b_],   (u64)0, __ATOMIC_RELAXED, __HIP_MEMORY_SCOPE_AGENT);
      aA[2*k2+1] = __hip_atomic_fetch_add((u64*)&hexw[b_+2], (u64)0, __ATOMIC_RELAXED, __HIP_MEMORY_SCOPE_AGENT);
    }
    #pragma unroll
    for (int k2=0;k2<4;k2++) {
      u32 b_ = gbase + (u32)((4+k2)*16);
      aB[2*k2]   = __hip_atomic_fetch_add((u64*)&hexw[b_],   (u64)0, __ATOMIC_RELAXED, __HIP_MEMORY_SCOPE_AGENT);
      aB[2*k2+1] = __hip_atomic_fetch_add((u64*)&hexw[b_+2], (u64)0, __ATOMIC_RELAXED, __HIP_MEMORY_SCOPE_AGENT);
    }
    f32x4 aR[2] = {{0.f,0.f,0.f,0.f},{0.f,0.f,0.f,0.f}};
    f32x4 aZ[2] = {{0.f,0.f,0.f,0.f},{0.f,0.f,0.f,0.f}};
    f32x4 aN[2] = {{0.f,0.f,0.f,0.f},{0.f,0.f,0.f,0.f}};
    #define MFMA4(BUF, KK0)                                                   \
      _Pragma("unroll")                                                       \
      for (int k2=0;k2<4;k2++) {                                              \
        union { u64 q[2]; bf16x8 v; } ab;                                     \
        ab.q[0] = BUF[2*k2]; ab.q[1] = BUF[2*k2+1];                           \
        _Pragma("unroll")                                                     \
        for (int c=0;c<2;c++) {                                               \
          aR[c] = __builtin_amdgcn_mfma_f32_16x16x32_bf16(ab.v, wreg[c][0][KK0+k2], aR[c],0,0,0); \
          aZ[c] = __builtin_amdgcn_mfma_f32_16x16x32_bf16(ab.v, wreg[c][1][KK0+k2], aZ[c],0,0,0); \
          aN[c] = __builtin_amdgcn_mfma_f32_16x16x32_bf16(ab.v, wreg[c][2][KK0+k2], aN[c],0,0,0); \
        }                                                                     \
      }
    MFMA4(aA, 0);
    #pragma unroll
    for (int k2=0;k2<4;k2++) {
      u32 b_ = gbase + (u32)((8+k2)*16);
      aA[2*k2]   = __hip_atomic_fetch_add((u64*)&hexw[b_],   (u64)0, __ATOMIC_RELAXED, __HIP_MEMORY_SCOPE_AGENT);
      aA[2*k2+1] = __hip_atomic_fetch_add((u64*)&hexw[b_+2], (u64)0, __ATOMIC_RELAXED, __HIP_MEMORY_SCOPE_AGENT);
    }
    MFMA4(aB, 4);
    #pragma unroll
    for (int k2=0;k2<4;k2++) {
      u32 b_ = gbase + (u32)((12+k2)*16);
      aB[2*k2]   = __hip_atomic_fetch_add((u64*)&hexw[b_],   (u64)0, __ATOMIC_RELAXED, __HIP_MEMORY_SCOPE_AGENT);
      aB[2*k2+1] = __hip_atomic_fetch_add((u64*)&hexw[b_+2], (u64)0, __ATOMIC_RELAXED, __HIP_MEMORY_SCOPE_AGENT);
    }
    MFMA4(aA, 8);
    MFMA4(aB, 12);
    #undef MFMA4

    // ---- fused elementwise: 2 col-halves x 4 batches, all in registers ----
    const u32 rb2 = (u32)((((s+1)&1)*2 + dir)*Bq + bg0)*256u;
    u16 hb[2][4]; float hn[2][4];
    #pragma unroll
    for (int c=0;c<2;c++)
    #pragma unroll
    for (int i=0;i<4;i++) {
      float rr = gxr[c][i] + aR[c][i] + bR[c];
      float zz = gxz[c][i] + aZ[c][i] + bZ[c];
      float gh =             aN[c][i] + bN[c];
      float r = 1.f/(1.f + __expf(-rr));
      float z = 1.f/(1.f + __expf(-zz));
      float x = gxn[c][i] + r*gh;
      x = fminf(fmaxf(x, -15.f), 15.f);
      float e2 = __expf(2.f*x);
      float n = (e2 - 1.f)/(e2 + 1.f);
      hn[c][i] = (1.f - z)*n + z*h[c][i];
      h[c][i] = hn[c][i]; hb[c][i] = f2bf(hn[c][i]);
    }
    // ---- publish 4 cols per u64 exchange (lane&3==0), straight from regs ----
    #pragma unroll
    for (int c=0;c<2;c++)
    #pragma unroll
    for (int i=0;i<4;i++) {
      u32 p1 = (u32)__shfl_down((int)hb[c][i], 1);
      u32 p2 = (u32)__shfl_down((int)hb[c][i], 2);
      u32 p3 = (u32)__shfl_down((int)hb[c][i], 3);
      if ((lane & 3) == 0) {
        u64 pk = (u64)hb[c][i] | ((u64)(p1 & 0xffffu) << 16)
               | ((u64)(p2 & 0xffffu) << 32) | ((u64)(p3 & 0xffffu) << 48);
        (void)__hip_atomic_exchange((u64*)&hexw[rb2 + (u32)(bq+i)*256u + (u32)(slice*16 + c*8 + (j0>>1))],
                                    pk, __ATOMIC_RELAXED, __HIP_MEMORY_SCOPE_AGENT);
      }
    }
    // drain exchanges (acked at MALL), then single signal.
    asm volatile("s_waitcnt vmcnt(0)" ::: "memory");
    if (lane == 0) {
      (void)__hip_atomic_fetch_add(&fl[slice], 1, __ATOMIC_RELAXED, __HIP_MEMORY_SCOPE_AGENT);
    }
    // ---- prefetch next step's gx (hides under next poll/gather) ----
    if (s+1 < Tq) ldgx(dir ? (Tq-2-s) : (s+1));
    // ---- off-critical-path output stores ----
    #pragma unroll
    for (int c=0;c<2;c++)
    #pragma unroll
    for (int i=0;i<4;i++) {
      int bg = bg0 + bq + i;
      size_t oi = ((size_t)bg*Tq + t_in)*1024 + dir*512 + jbase + c*16 + j0;
      if (LAYER==0) {
        __builtin_nontemporal_store(hb[c][i], &hs0[oi]);
      } else {
        if (bf16in) __builtin_nontemporal_store(hb[c][i], &((u16*)dout)[oi]);
        else        __builtin_nontemporal_store(hn[c][i], &((float*)dout)[oi]);
      }
      if (s == Tq-1) {
        size_t hyi = (size_t)Bq*Tq*1024 + ((size_t)(LAYER*2 + dir)*Bq + bg)*512 + jbase + c*16 + j0;
        if (bf16in) ((u16*)dout)[hyi] = hb[c][i];
        else        ((float*)dout)[hyi] = hn[c][i];
      }
    }
  }
}

__global__ void init_k(u32* hexw, int* flags){
  int i = blockIdx.x*256 + threadIdx.x;
  if (i < 2*2*Bq*256) hexw[i] = 0;
  if (i < 128) flags[i] = 0;
}

extern "C" void kernel_launch(void* const* d_in, const int* in_sizes, int n_in,
                              void* d_out, int out_size, void* d_ws, size_t ws_size,
                              hipStream_t stream)
{
  const void* xs    = d_in[0];
  const void* w_ih0 = d_in[1];
  const void* w_hh0 = d_in[2];
  const void* b_ih0 = d_in[3];
  const void* b_hh0 = d_in[4];
  const void* w_ih1 = d_in[5];
  const void* w_hh1 = d_in[6];
  const void* b_ih1 = d_in[7];
  const void* b_hh1 = d_in[8];
  (void)in_sizes; (void)n_in; (void)out_size;

  // ws layout, smalls first: dflag @0, flags @256, hexw @1024 (262144 B),
  // gx @263168: fp32 (402653184 B) if it fits, else bf16 (201326592 B).
  char* ws   = (char*)d_ws;
  int* dflag = (int*)ws;
  int* flags = (int*)(ws + 256);
  u32* hexw  = (u32*)(ws + 1024);
  void* gx   = (void*)(ws + 263168ULL);
  const bool gxf32 = ws_size >= 263168ULL + 402653184ULL;
  // hs0: bf16 scratch in d_out bytes [0, 67 MB); gemm1 consumes it before
  // scan1 overwrites d_out with h1_out (stream-ordered).
  u16* hs0   = (u16*)d_out;

  dim3 gg(Tq*Bq/64, G3/64, 2);   // (512, 24, 2)

  detect_k<<<1, 256, 0, stream>>>((const u16*)xs, dflag);
  init_k<<<512, 256, 0, stream>>>(hexw, flags);
  if (gxf32) {
    gemm_gx<512,0,1><<<gg, 256, 0, stream>>>(xs, w_ih0, b_ih0, gx, dflag);
    gru_scan<0,1><<<128, 64, 0, stream>>>(w_hh0, b_hh0, gx, hs0, d_out, hexw, flags, dflag);
    gemm_gx<1024,1,1><<<gg, 256, 0, stream>>>(hs0, w_ih1, b_ih1, gx, dflag);
    init_k<<<512, 256, 0, stream>>>(hexw, flags);
    gru_scan<1,1><<<128, 64, 0, stream>>>(w_hh1, b_hh1, gx, hs0, d_out, hexw, flags, dflag);
  } else {
    gemm_gx<512,0,0><<<gg, 256, 0, stream>>>(xs, w_ih0, b_ih0, gx, dflag);
    gru_scan<0,0><<<128, 64, 0, stream>>>(w_hh0, b_hh0, gx, hs0, d_out, hexw, flags, dflag);
    gemm_gx<1024,1,0><<<gg, 256, 0, stream>>>(hs0, w_ih1, b_ih1, gx, dflag);
    init_k<<<512, 256, 0, stream>>>(hexw, flags);
    gru_scan<1,0><<<128, 64, 0, stream>>>(w_hh1, b_hh1, gx, hs0, d_out, hexw, flags, dflag);
  }
}

// Round 11
// 6523.648 us; speedup vs baseline: 1.1794x; 1.1794x over previous
//
#include <hip/hip_runtime.h>
#include <stdint.h>

#define Bq 64
#define Tq 512
#define Hq 512
#define G3 1536

typedef unsigned short u16;
typedef uint32_t u32;
typedef unsigned long long u64;
typedef __attribute__((ext_vector_type(8))) short bf16x8;
typedef __attribute__((ext_vector_type(4))) float f32x4;

__device__ __forceinline__ float bf2f(u16 v){ unsigned u = ((unsigned)v)<<16; float f; __builtin_memcpy(&f,&u,4); return f; }
__device__ __forceinline__ u16 f2bf(float f){ unsigned u; __builtin_memcpy(&u,&f,4); u += 0x7fffu + ((u>>16)&1u); return (u16)(u>>16); }

// dtype detector: flag=1 if inputs are bf16, 0 if fp32.
__global__ void detect_k(const u16* __restrict__ xs, int* __restrict__ flag){
  __shared__ int cnt;
  if (threadIdx.x==0) cnt = 0;
  __syncthreads();
  int good = 0;
  for (int i = threadIdx.x; i < 4096; i += 256) {
    u16 v = xs[2*i];
    int e = (v>>7)&0xFF;
    if (e==0 || (e>=100 && e<=140)) good++;
  }
  atomicAdd(&cnt, good);
  __syncthreads();
  if (threadIdx.x==0) flag[0] = (cnt > 3600) ? 1 : 0;
}

// ---------------------------------------------------------------------------
// gx GEMM, 128x128 tile (staging/output ratio 1.0 vs 2.0 at 64^2; MFMA:ds
// 3:1). Per-output-element accumulation order (kb asc, ks asc, hi -> A-lo ->
// W-lo) is IDENTICAL to the verified 64^2 version -> gx bit-identical.
// AMODE 0: A dtype per flag (fp32 -> split hi/lo bf16). AMODE 1: A bf16 (hs0).
// OUTF32: gx stored fp32 (1) or bf16 (0). Dynamic LDS 73728 B.
// ---------------------------------------------------------------------------
template<int K, int AMODE, int OUTF32>
__global__ __launch_bounds__(256,1) void gemm_gx(const void* __restrict__ Araw,
        const void* __restrict__ Wraw, const void* __restrict__ braw,
        void* __restrict__ outraw, const int* __restrict__ dflag)
{
  extern __shared__ __align__(16) char gsm[];
  u16* Ah = (u16*)gsm;                    // 128 x 72 = 18432 B
  u16* Al = (u16*)(gsm + 18432);
  u16* Wh = (u16*)(gsm + 36864);
  u16* Wl = (u16*)(gsm + 55296);          // total 73728 B
  const int bf16in = dflag[0];
  const bool useAlo = (AMODE==0) && !bf16in;
  const bool useWlo = !bf16in;
  const int dir = blockIdx.z;
  const int tid = threadIdx.x;
  const int m0 = blockIdx.x*128, n0 = blockIdx.y*128;
  const int wave = tid>>6, lane = tid&63;
  const int wm = (wave>>1)*64, wn = (wave&1)*64;
  f32x4 acc[4][4] = {};

  for (int kb=0; kb<K/64; kb++) {
    if (AMODE==0 && !bf16in) {
      const float* Af = (const float*)Araw;
      #pragma unroll
      for (int it=0; it<8; it++) {
        int c = it*256 + tid;
        int r = c>>4, cc = (c&15)*4;
        float4 v = *(const float4*)&Af[(size_t)(m0+r)*K + kb*64 + cc];
        u16 h0=f2bf(v.x), h1=f2bf(v.y), h2=f2bf(v.z), h3=f2bf(v.w);
        *(ushort4*)&Ah[r*72+cc] = make_ushort4(h0,h1,h2,h3);
        *(ushort4*)&Al[r*72+cc] = make_ushort4(
            f2bf(v.x-bf2f(h0)), f2bf(v.y-bf2f(h1)),
            f2bf(v.z-bf2f(h2)), f2bf(v.w-bf2f(h3)));
      }
    } else {
      const u16* Ab = (const u16*)Araw;
      #pragma unroll
      for (int it=0; it<4; it++) {
        int c = it*256 + tid;
        int r = c>>3, cc = (c&7)*8;
        *(bf16x8*)&Ah[r*72+cc] = *(const bf16x8*)&Ab[(size_t)(m0+r)*K + kb*64 + cc];
      }
    }
    if (!bf16in) {
      const float* Wf = (const float*)Wraw + (size_t)dir*G3*K;
      #pragma unroll
      for (int it=0; it<8; it++) {
        int c = it*256 + tid;
        int r = c>>4, cc = (c&15)*4;
        float4 v = *(const float4*)&Wf[(size_t)(n0+r)*K + kb*64 + cc];
        u16 h0=f2bf(v.x), h1=f2bf(v.y), h2=f2bf(v.z), h3=f2bf(v.w);
        *(ushort4*)&Wh[r*72+cc] = make_ushort4(h0,h1,h2,h3);
        *(ushort4*)&Wl[r*72+cc] = make_ushort4(
            f2bf(v.x-bf2f(h0)), f2bf(v.y-bf2f(h1)),
            f2bf(v.z-bf2f(h2)), f2bf(v.w-bf2f(h3)));
      }
    } else {
      const u16* Wb = (const u16*)Wraw + (size_t)dir*G3*K;
      #pragma unroll
      for (int it=0; it<4; it++) {
        int c = it*256 + tid;
        int r = c>>3, cc = (c&7)*8;
        *(bf16x8*)&Wh[r*72+cc] = *(const bf16x8*)&Wb[(size_t)(n0+r)*K + kb*64 + cc];
      }
    }
    __syncthreads();
    #pragma unroll
    for (int ks=0; ks<2; ks++) {
      int ko = ks*32 + (lane>>4)*8;
      bf16x8 ah[4], bh[4];
      #pragma unroll
      for (int i=0;i<4;i++) ah[i] = *(const bf16x8*)&Ah[(wm + i*16 + (lane&15))*72 + ko];
      #pragma unroll
      for (int j=0;j<4;j++) bh[j] = *(const bf16x8*)&Wh[(wn + j*16 + (lane&15))*72 + ko];
      #pragma unroll
      for (int i=0;i<4;i++)
      #pragma unroll
      for (int j=0;j<4;j++)
        acc[i][j] = __builtin_amdgcn_mfma_f32_16x16x32_bf16(ah[i],bh[j],acc[i][j],0,0,0);
      if (useAlo) {
        bf16x8 al[4];
        #pragma unroll
        for (int i=0;i<4;i++) al[i] = *(const bf16x8*)&Al[(wm + i*16 + (lane&15))*72 + ko];
        #pragma unroll
        for (int i=0;i<4;i++)
        #pragma unroll
        for (int j=0;j<4;j++)
          acc[i][j] = __builtin_amdgcn_mfma_f32_16x16x32_bf16(al[i],bh[j],acc[i][j],0,0,0);
      }
      if (useWlo) {
        bf16x8 bl[4];
        #pragma unroll
        for (int j=0;j<4;j++) bl[j] = *(const bf16x8*)&Wl[(wn + j*16 + (lane&15))*72 + ko];
        #pragma unroll
        for (int i=0;i<4;i++)
        #pragma unroll
        for (int j=0;j<4;j++)
          acc[i][j] = __builtin_amdgcn_mfma_f32_16x16x32_bf16(ah[i],bl[j],acc[i][j],0,0,0);
      }
    }
    __syncthreads();
  }
  #pragma unroll
  for (int i=0;i<4;i++) {
    #pragma unroll
    for (int j=0;j<4;j++) {
      int nn = n0 + wn + j*16 + (lane&15);
      float bv = bf16in ? bf2f(((const u16*)braw)[dir*G3 + nn])
                        : ((const float*)braw)[dir*G3 + nn];
      #pragma unroll
      for (int r=0;r<4;r++) {
        int mm = m0 + wm + i*16 + (lane>>4)*4 + r;
        int b = mm >> 9, t = mm & 511;
        size_t oi = ((size_t)(dir*Tq + t)*Bq + b)*G3 + nn;
        float v = acc[i][j][r] + bv;
        if (OUTF32) ((float*)outraw)[oi] = v;
        else        ((u16*)outraw)[oi]   = f2bf(v);
      }
    }
  }
}

// ---------------------------------------------------------------------------
// Persistent GRU scan — EXACT round-9 kernel (proven 2,437 us/dispatch).
// 128 wgs: dir(2) x batch-group(4) x slice(16). Single 64-lane compute wave
// + one weight-staging helper wave. ALL-RMW coherence-point protocol.
// Round-10 lesson encoded: W_hh stays in LDS — the full-reg variant needs
// 384 VGPRs of payload but the arch-VGPR file caps at 256/wave (512 only
// with AGPRs, which the allocator won't use for MFMA A/B arrays) -> silent
// scratch spill, +95 MB WRITE_SIZE, -29% perf.
// ---------------------------------------------------------------------------
template<int LAYER, int GXF32>
__global__ __launch_bounds__(128,1) void gru_scan(const void* __restrict__ whh,
        const void* __restrict__ bhh, const void* __restrict__ gx,
        u16* __restrict__ hs0, void* __restrict__ dout,
        u32* __restrict__ hexw, int* __restrict__ flags,
        const int* __restrict__ dflag)
{
  extern __shared__ char smem[];
  u16* wlds = (u16*)smem;                 // 96 x 520 bf16 = 99840 B

  const int bf16in = dflag[0];
  const int tid = threadIdx.x;
  const int bx  = blockIdx.x;
  const int dir = bx>>6, group=(bx>>4)&3, slice=bx&15;
  const int jbase = slice*32, bg0 = group*16;
  int* fl = flags + (dir*4+group)*16;

  // ---- weight staging (both waves), then helper wave exits ----
  if (!bf16in) {
    const float* wf = (const float*)whh + (size_t)dir*G3*Hq;
    for (int c = tid; c < 96*128; c += 128) {
      int r = c>>7, q = (c&127)*4;
      int gate = r>>5, jj = r&31;
      float4 v = *(const float4*)&wf[(size_t)(gate*512 + jbase + jj)*Hq + q];
      *(ushort4*)&wlds[r*520 + q] = make_ushort4(f2bf(v.x),f2bf(v.y),f2bf(v.z),f2bf(v.w));
    }
  } else {
    const u16* wb = (const u16*)whh + (size_t)dir*G3*Hq;
    for (int c = tid; c < 96*64; c += 128) {
      int r = c>>6, cc = (c&63)*8;
      int gate = r>>5, jj = r&31;
      *(bf16x8*)&wlds[r*520 + cc] = *(const bf16x8*)&wb[(size_t)(gate*512 + jbase + jj)*Hq + cc];
    }
  }
  __syncthreads();
  if (tid >= 64) return;                  // helper wave done

  const int lane = tid;                   // 0..63
  const int j0 = lane&15;
  const int bq = (lane>>4)*4;             // batch base 0,4,8,12

  // loop-invariant bias regs (both col-halves)
  float bR[2], bZ[2], bN[2];
  #pragma unroll
  for (int c=0;c<2;c++) {
    int off = dir*G3 + jbase + c*16 + j0;
    if (bf16in) { const u16* bb=(const u16*)bhh;
      bR[c]=bf2f(bb[off]); bZ[c]=bf2f(bb[off+512]); bN[c]=bf2f(bb[off+1024]); }
    else { const float* bb=(const float*)bhh;
      bR[c]=bb[off]; bZ[c]=bb[off+512]; bN[c]=bb[off+1024]; }
  }

  float h[2][4] = {};
  float gxr[2][4], gxz[2][4], gxn[2][4];
  auto ldgx = [&](int t_in_){
    #pragma unroll
    for (int c=0;c<2;c++)
    #pragma unroll
    for (int i=0;i<4;i++){
      size_t gb = ((size_t)(dir*Tq + t_in_)*Bq + (bg0 + bq + i))*G3 + jbase + c*16 + j0;
      if (GXF32) { const float* gp=(const float*)gx + gb;
        gxr[c][i]=gp[0]; gxz[c][i]=gp[512]; gxn[c][i]=gp[1024]; }
      else { const u16* gp=(const u16*)gx + gb;
        gxr[c][i]=bf2f(gp[0]); gxz[c][i]=bf2f(gp[512]); gxn[c][i]=bf2f(gp[1024]); }
    }
  };
  ldgx(dir ? (Tq-1) : 0);

  for (int s=0; s<Tq; s++) {
    const int t_in = dir ? (Tq-1-s) : s;
    // poll (lanes 0-15, RMW at MALL); reconvergence = intra-wave barrier.
    if (lane < 16) {
      while (__hip_atomic_fetch_add(&fl[lane], 0, __ATOMIC_RELAXED, __HIP_MEMORY_SCOPE_AGENT) < s) {
        __builtin_amdgcn_s_sleep(1);
      }
    }
    asm volatile("" ::: "memory");   // compiler-only: no hoisting of gathers
    // ---- issue all 32 A-fragment u64 RMW gathers straight into VGPRs ----
    const u32 rb = (u32)(((s&1)*2 + dir)*Bq + bg0)*256u;
    u64 areg[32];
    #pragma unroll
    for (int kk=0; kk<16; kk++) {
      u32 base = rb + (u32)(lane&15)*256u + (u32)(kk*16 + (lane>>4)*4);
      areg[2*kk]   = __hip_atomic_fetch_add((u64*)&hexw[base],   (u64)0, __ATOMIC_RELAXED, __HIP_MEMORY_SCOPE_AGENT);
      areg[2*kk+1] = __hip_atomic_fetch_add((u64*)&hexw[base+2], (u64)0, __ATOMIC_RELAXED, __HIP_MEMORY_SCOPE_AGENT);
    }
    // ---- 6 MFMA chains, fragments consumed in kk order as they return ----
    f32x4 aR[2] = {{0.f,0.f,0.f,0.f},{0.f,0.f,0.f,0.f}};
    f32x4 aZ[2] = {{0.f,0.f,0.f,0.f},{0.f,0.f,0.f,0.f}};
    f32x4 aN[2] = {{0.f,0.f,0.f,0.f},{0.f,0.f,0.f,0.f}};
    #pragma unroll
    for (int kk=0; kk<16; kk++) {
      union { u64 q[2]; bf16x8 v; } ab;
      ab.q[0] = areg[2*kk]; ab.q[1] = areg[2*kk+1];
      int ko = kk*32 + (lane>>4)*8;
      #pragma unroll
      for (int c=0;c<2;c++) {
        int wl = c*16 + j0;
        bf16x8 b0 = *(const bf16x8*)&wlds[(     wl)*520 + ko];
        bf16x8 b1 = *(const bf16x8*)&wlds[(32 + wl)*520 + ko];
        bf16x8 b2 = *(const bf16x8*)&wlds[(64 + wl)*520 + ko];
        aR[c] = __builtin_amdgcn_mfma_f32_16x16x32_bf16(ab.v,b0,aR[c],0,0,0);
        aZ[c] = __builtin_amdgcn_mfma_f32_16x16x32_bf16(ab.v,b1,aZ[c],0,0,0);
        aN[c] = __builtin_amdgcn_mfma_f32_16x16x32_bf16(ab.v,b2,aN[c],0,0,0);
      }
    }
    // ---- fused elementwise: 2 col-halves x 4 batches, all in registers ----
    const u32 rb2 = (u32)((((s+1)&1)*2 + dir)*Bq + bg0)*256u;
    u16 hb[2][4]; float hn[2][4];
    #pragma unroll
    for (int c=0;c<2;c++)
    #pragma unroll
    for (int i=0;i<4;i++) {
      float rr = gxr[c][i] + aR[c][i] + bR[c];
      float zz = gxz[c][i] + aZ[c][i] + bZ[c];
      float gh =             aN[c][i] + bN[c];
      float r = 1.f/(1.f + __expf(-rr));
      float z = 1.f/(1.f + __expf(-zz));
      float x = gxn[c][i] + r*gh;
      x = fminf(fmaxf(x, -15.f), 15.f);
      float e2 = __expf(2.f*x);
      float n = (e2 - 1.f)/(e2 + 1.f);
      hn[c][i] = (1.f - z)*n + z*h[c][i];
      h[c][i] = hn[c][i]; hb[c][i] = f2bf(hn[c][i]);
    }
    // ---- publish 4 cols per u64 exchange (lane&3==0), straight from regs ----
    #pragma unroll
    for (int c=0;c<2;c++)
    #pragma unroll
    for (int i=0;i<4;i++) {
      u32 p1 = (u32)__shfl_down((int)hb[c][i], 1);
      u32 p2 = (u32)__shfl_down((int)hb[c][i], 2);
      u32 p3 = (u32)__shfl_down((int)hb[c][i], 3);
      if ((lane & 3) == 0) {
        u64 pk = (u64)hb[c][i] | ((u64)(p1 & 0xffffu) << 16)
               | ((u64)(p2 & 0xffffu) << 32) | ((u64)(p3 & 0xffffu) << 48);
        (void)__hip_atomic_exchange((u64*)&hexw[rb2 + (u32)(bq+i)*256u + (u32)(slice*16 + c*8 + (j0>>1))],
                                    pk, __ATOMIC_RELAXED, __HIP_MEMORY_SCOPE_AGENT);
      }
    }
    // drain exchanges (acked at MALL), then single signal.
    asm volatile("s_waitcnt vmcnt(0)" ::: "memory");
    if (lane == 0) {
      (void)__hip_atomic_fetch_add(&fl[slice], 1, __ATOMIC_RELAXED, __HIP_MEMORY_SCOPE_AGENT);
    }
    // ---- prefetch next step's gx (hides under next poll/gather) ----
    if (s+1 < Tq) ldgx(dir ? (Tq-2-s) : (s+1));
    // ---- off-critical-path output stores ----
    #pragma unroll
    for (int c=0;c<2;c++)
    #pragma unroll
    for (int i=0;i<4;i++) {
      int bg = bg0 + bq + i;
      size_t oi = ((size_t)bg*Tq + t_in)*1024 + dir*512 + jbase + c*16 + j0;
      if (LAYER==0) {
        __builtin_nontemporal_store(hb[c][i], &hs0[oi]);
      } else {
        if (bf16in) __builtin_nontemporal_store(hb[c][i], &((u16*)dout)[oi]);
        else        __builtin_nontemporal_store(hn[c][i], &((float*)dout)[oi]);
      }
      if (s == Tq-1) {
        size_t hyi = (size_t)Bq*Tq*1024 + ((size_t)(LAYER*2 + dir)*Bq + bg)*512 + jbase + c*16 + j0;
        if (bf16in) ((u16*)dout)[hyi] = hb[c][i];
        else        ((float*)dout)[hyi] = hn[c][i];
      }
    }
  }
}

__global__ void init_k(u32* hexw, int* flags){
  int i = blockIdx.x*256 + threadIdx.x;
  if (i < 2*2*Bq*256) hexw[i] = 0;
  if (i < 128) flags[i] = 0;
}

extern "C" void kernel_launch(void* const* d_in, const int* in_sizes, int n_in,
                              void* d_out, int out_size, void* d_ws, size_t ws_size,
                              hipStream_t stream)
{
  const void* xs    = d_in[0];
  const void* w_ih0 = d_in[1];
  const void* w_hh0 = d_in[2];
  const void* b_ih0 = d_in[3];
  const void* b_hh0 = d_in[4];
  const void* w_ih1 = d_in[5];
  const void* w_hh1 = d_in[6];
  const void* b_ih1 = d_in[7];
  const void* b_hh1 = d_in[8];
  (void)in_sizes; (void)n_in; (void)out_size;

  // ws layout, smalls first: dflag @0, flags @256, hexw @1024 (262144 B),
  // gx @263168: fp32 (402653184 B) if it fits, else bf16 (201326592 B).
  char* ws   = (char*)d_ws;
  int* dflag = (int*)ws;
  int* flags = (int*)(ws + 256);
  u32* hexw  = (u32*)(ws + 1024);
  void* gx   = (void*)(ws + 263168ULL);
  const bool gxf32 = ws_size >= 263168ULL + 402653184ULL;
  // hs0: bf16 scratch in d_out bytes [0, 67 MB); gemm1 consumes it before
  // scan1 overwrites d_out with h1_out (stream-ordered).
  u16* hs0   = (u16*)d_out;

  hipFuncSetAttribute((const void*)gru_scan<0,0>, hipFuncAttributeMaxDynamicSharedMemorySize, 99840);
  hipFuncSetAttribute((const void*)gru_scan<1,0>, hipFuncAttributeMaxDynamicSharedMemorySize, 99840);
  hipFuncSetAttribute((const void*)gru_scan<0,1>, hipFuncAttributeMaxDynamicSharedMemorySize, 99840);
  hipFuncSetAttribute((const void*)gru_scan<1,1>, hipFuncAttributeMaxDynamicSharedMemorySize, 99840);
  hipFuncSetAttribute((const void*)gemm_gx<512,0,1>,  hipFuncAttributeMaxDynamicSharedMemorySize, 73728);
  hipFuncSetAttribute((const void*)gemm_gx<1024,1,1>, hipFuncAttributeMaxDynamicSharedMemorySize, 73728);
  hipFuncSetAttribute((const void*)gemm_gx<512,0,0>,  hipFuncAttributeMaxDynamicSharedMemorySize, 73728);
  hipFuncSetAttribute((const void*)gemm_gx<1024,1,0>, hipFuncAttributeMaxDynamicSharedMemorySize, 73728);

  dim3 gg(Tq*Bq/128, G3/128, 2);   // (256, 12, 2)

  detect_k<<<1, 256, 0, stream>>>((const u16*)xs, dflag);
  init_k<<<512, 256, 0, stream>>>(hexw, flags);
  if (gxf32) {
    gemm_gx<512,0,1><<<gg, 256, 73728, stream>>>(xs, w_ih0, b_ih0, gx, dflag);
    gru_scan<0,1><<<128, 128, 99840, stream>>>(w_hh0, b_hh0, gx, hs0, d_out, hexw, flags, dflag);
    gemm_gx<1024,1,1><<<gg, 256, 73728, stream>>>(hs0, w_ih1, b_ih1, gx, dflag);
    init_k<<<512, 256, 0, stream>>>(hexw, flags);
    gru_scan<1,1><<<128, 128, 99840, stream>>>(w_hh1, b_hh1, gx, hs0, d_out, hexw, flags, dflag);
  } else {
    gemm_gx<512,0,0><<<gg, 256, 73728, stream>>>(xs, w_ih0, b_ih0, gx, dflag);
    gru_scan<0,0><<<128, 128, 99840, stream>>>(w_hh0, b_hh0, gx, hs0, d_out, hexw, flags, dflag);
    gemm_gx<1024,1,0><<<gg, 256, 73728, stream>>>(hs0, w_ih1, b_ih1, gx, dflag);
    init_k<<<512, 256, 0, stream>>>(hexw, flags);
    gru_scan<1,0><<<128, 128, 99840, stream>>>(w_hh1, b_hh1, gx, hs0, d_out, hexw, flags, dflag);
  }
}